// Round 8
// baseline (26.431 us; speedup 1.0000x reference)
//
#include <hip/hip_runtime.h>

// CrossNet flattened (affine in x0):
//   out = x*(1+s1+s2+s3) + (b1+b2+b3)
//   a_i = x.k_i (independent dots on original x); c2=b1.k2, c3=(b1+b2).k3
//   s1=a1; s2=(1+s1)*a2+c2; s3=(1+s1+s2)*a3+c3
// R7: 4 rows per wave. R6 post-mortem: k/b vector loads were 196 MB of
// L1/L2 return traffic device-wide (1.5x the x stream) — amortize 2x by
// doubling rows/wave. Flattened state is lean (R6: 40 VGPR), so 4 rows
// fits ~110 VGPR -> 4 waves/SIMD, matching the 4-blocks/CU grid.
// Butterflies: 14 interleaved chains, 6 deep. NT stores kept (write-once
// out; keeps L3 clean for replay-resident x). NT loads NOT used (R2: x is
// L3-resident across replays; bypassing L3 cost +6%).

#define CN_BATCH 16384
#define CN_DIM   1024
#define CN_ROWS  4          // rows per wave

typedef float f32x4 __attribute__((ext_vector_type(4)));

__global__ __launch_bounds__(256) void crossnet_kernel(
    const float* __restrict__ x,
    const float* __restrict__ kernels,
    const float* __restrict__ bias,
    float* __restrict__ out)
{
    const int wave = threadIdx.x >> 6;              // 0..3
    const int lane = threadIdx.x & 63;
    const int base = ((blockIdx.x << 2) + wave) * CN_ROWS;   // first of 4 rows
    const int eoff = lane * 4;

    const float* k1 = kernels;
    const float* k2 = kernels + CN_DIM;
    const float* k3 = kernels + 2 * CN_DIM;
    const float* b1 = bias;
    const float* b2 = bias + CN_DIM;
    const float* b3 = bias + 2 * CN_DIM;

    // Load 4 x rows (coalesced 16B/lane; lane l covers {j*256+4l..+3}).
    f32x4 x0[CN_ROWS][4];
#pragma unroll
    for (int r = 0; r < CN_ROWS; ++r) {
        const float* xr = x + (size_t)(base + r) * CN_DIM;
#pragma unroll
        for (int j = 0; j < 4; ++j)
            x0[r][j] = *reinterpret_cast<const f32x4*>(xr + j * 256 + eoff);
    }

    // One dot pass: 12 row-dots (a1..a3 x 4 rows) + c2, c3 + Bsum.
    float a1[CN_ROWS], a2[CN_ROWS], a3[CN_ROWS];
#pragma unroll
    for (int r = 0; r < CN_ROWS; ++r) { a1[r] = 0.f; a2[r] = 0.f; a3[r] = 0.f; }
    float c2 = 0.f, c3 = 0.f;
    f32x4 Bs[4];

#pragma unroll
    for (int j = 0; j < 4; ++j) {
        f32x4 vk1 = *reinterpret_cast<const f32x4*>(k1 + j * 256 + eoff);
        f32x4 vk2 = *reinterpret_cast<const f32x4*>(k2 + j * 256 + eoff);
        f32x4 vk3 = *reinterpret_cast<const f32x4*>(k3 + j * 256 + eoff);
        f32x4 vb1 = *reinterpret_cast<const f32x4*>(b1 + j * 256 + eoff);
        f32x4 vb2 = *reinterpret_cast<const f32x4*>(b2 + j * 256 + eoff);
        f32x4 vb3 = *reinterpret_cast<const f32x4*>(b3 + j * 256 + eoff);
        f32x4 b12 = vb1 + vb2;
        Bs[j] = b12 + vb3;
#pragma unroll
        for (int c = 0; c < 4; ++c) {
#pragma unroll
            for (int r = 0; r < CN_ROWS; ++r) {
                a1[r] = fmaf(x0[r][j][c], vk1[c], a1[r]);
                a2[r] = fmaf(x0[r][j][c], vk2[c], a2[r]);
                a3[r] = fmaf(x0[r][j][c], vk3[c], a3[r]);
            }
            c2 = fmaf(vb1[c], vk2[c], c2);
            c3 = fmaf(b12[c], vk3[c], c3);
        }
    }

    // 14 fully-interleaved 64-lane butterflies (6 deep).
#pragma unroll
    for (int o = 32; o >= 1; o >>= 1) {
#pragma unroll
        for (int r = 0; r < CN_ROWS; ++r) {
            a1[r] += __shfl_xor(a1[r], o, 64);
            a2[r] += __shfl_xor(a2[r], o, 64);
            a3[r] += __shfl_xor(a3[r], o, 64);
        }
        c2 += __shfl_xor(c2, o, 64);
        c3 += __shfl_xor(c3, o, 64);
    }

    // Scalar recurrence + single update pass per row; NT stores (write-once).
#pragma unroll
    for (int r = 0; r < CN_ROWS; ++r) {
        const float t1 = 1.0f + a1[r];
        const float s2 = fmaf(t1, a2[r], c2);
        const float t2 = t1 + s2;
        const float s3 = fmaf(t2, a3[r], c3);
        const float t3 = t2 + s3;

        float* orow = out + (size_t)(base + r) * CN_DIM;
#pragma unroll
        for (int j = 0; j < 4; ++j) {
            f32x4 o;
#pragma unroll
            for (int c = 0; c < 4; ++c)
                o[c] = fmaf(x0[r][j][c], t3, Bs[j][c]);
            __builtin_nontemporal_store(o,
                reinterpret_cast<f32x4*>(orow + j * 256 + eoff));
        }
    }
}

extern "C" void kernel_launch(void* const* d_in, const int* in_sizes, int n_in,
                              void* d_out, int out_size, void* d_ws, size_t ws_size,
                              hipStream_t stream) {
    const float* x       = (const float*)d_in[0];
    const float* kernels = (const float*)d_in[1];
    const float* bias    = (const float*)d_in[2];
    float* out           = (float*)d_out;

    // 4 rows/wave, 4 waves/block -> 16 rows/block.
    dim3 grid(CN_BATCH / 16);
    dim3 block(256);
    crossnet_kernel<<<grid, block, 0, stream>>>(x, kernels, bias, out);
}

// Round 9
// 24.901 us; speedup vs baseline: 1.0614x; 1.0614x over previous
//
#include <hip/hip_runtime.h>

// CrossNet flattened (affine in x0):
//   out = x*(1+s1+s2+s3) + (b1+b2+b3)
//   a_i = x.k_i (independent dots on original x); c2=b1.k2, c3=(b1+b2).k3
//   s1=a1; s2=(1+s1)*a2+c2; s3=(1+s1+s2)*a3+c3
// R8: exact revert to R6 (best: 24.90us). Config sweep is now bracketed:
//   1 row/wave 28.8us | 2 rows/wave 24.90us | 4 rows/wave 26.4us (R7:
//   grid 1024 -> 16 waves/CU, TLP halved; R4: VGPR-driven occupancy loss).
// 2 rows/wave + 2048 blocks = 32 waves/CU (hardware max TLP) + 40 VGPR.
// NT stores only (R5 +0.75us win; R2 showed NT loads hurt: x is L3-resident
// across graph replays). Effective 5.39 TB/s = 86% of measured copy ceiling.

#define CN_BATCH 16384
#define CN_DIM   1024

typedef float f32x4 __attribute__((ext_vector_type(4)));

__global__ __launch_bounds__(256) void crossnet_kernel(
    const float* __restrict__ x,
    const float* __restrict__ kernels,
    const float* __restrict__ bias,
    float* __restrict__ out)
{
    const int wave = threadIdx.x >> 6;              // 0..3
    const int lane = threadIdx.x & 63;
    const int pair = (blockIdx.x << 2) + wave;
    const int rowA = pair * 2;                      // two adjacent rows per wave
    const int eoff = lane * 4;

    const float* xrowA = x + (size_t)rowA * CN_DIM;
    const float* xrowB = xrowA + CN_DIM;

    const float* k1 = kernels;
    const float* k2 = kernels + CN_DIM;
    const float* k3 = kernels + 2 * CN_DIM;
    const float* b1 = bias;
    const float* b2 = bias + CN_DIM;
    const float* b3 = bias + 2 * CN_DIM;

    // Load both x rows (coalesced 16B/lane; lane l covers {j*256+4l..+3}).
    f32x4 x0A[4], x0B[4];
#pragma unroll
    for (int j = 0; j < 4; ++j) {
        x0A[j] = *reinterpret_cast<const f32x4*>(xrowA + j * 256 + eoff);
        x0B[j] = *reinterpret_cast<const f32x4*>(xrowB + j * 256 + eoff);
    }

    // One pass: 6 row-dots (a1..a3 x 2 rows) + 2 shared dots (c2,c3) + Bsum.
    float a1A = 0.f, a2A = 0.f, a3A = 0.f;
    float a1B = 0.f, a2B = 0.f, a3B = 0.f;
    float c2  = 0.f, c3  = 0.f;
    f32x4 Bs[4];
#pragma unroll
    for (int j = 0; j < 4; ++j) {
        f32x4 vk1 = *reinterpret_cast<const f32x4*>(k1 + j * 256 + eoff);
        f32x4 vk2 = *reinterpret_cast<const f32x4*>(k2 + j * 256 + eoff);
        f32x4 vk3 = *reinterpret_cast<const f32x4*>(k3 + j * 256 + eoff);
        f32x4 vb1 = *reinterpret_cast<const f32x4*>(b1 + j * 256 + eoff);
        f32x4 vb2 = *reinterpret_cast<const f32x4*>(b2 + j * 256 + eoff);
        f32x4 vb3 = *reinterpret_cast<const f32x4*>(b3 + j * 256 + eoff);
        f32x4 b12 = vb1 + vb2;
        Bs[j] = b12 + vb3;
#pragma unroll
        for (int c = 0; c < 4; ++c) {
            a1A = fmaf(x0A[j][c], vk1[c], a1A);
            a2A = fmaf(x0A[j][c], vk2[c], a2A);
            a3A = fmaf(x0A[j][c], vk3[c], a3A);
            a1B = fmaf(x0B[j][c], vk1[c], a1B);
            a2B = fmaf(x0B[j][c], vk2[c], a2B);
            a3B = fmaf(x0B[j][c], vk3[c], a3B);
            c2  = fmaf(vb1[c],    vk2[c], c2);
            c3  = fmaf(b12[c],    vk3[c], c3);
        }
    }

    // 8 fully-interleaved 64-lane butterflies (6-deep serial, not 18).
#pragma unroll
    for (int o = 32; o >= 1; o >>= 1) {
        a1A += __shfl_xor(a1A, o, 64);
        a2A += __shfl_xor(a2A, o, 64);
        a3A += __shfl_xor(a3A, o, 64);
        a1B += __shfl_xor(a1B, o, 64);
        a2B += __shfl_xor(a2B, o, 64);
        a3B += __shfl_xor(a3B, o, 64);
        c2  += __shfl_xor(c2,  o, 64);
        c3  += __shfl_xor(c3,  o, 64);
    }

    // Scalar recurrence (per row): t_l = 1 + s1 + ... + s_l.
    const float t1A = 1.0f + a1A;
    const float s2A = fmaf(t1A, a2A, c2);
    const float t2A = t1A + s2A;
    const float s3A = fmaf(t2A, a3A, c3);
    const float t3A = t2A + s3A;

    const float t1B = 1.0f + a1B;
    const float s2B = fmaf(t1B, a2B, c2);
    const float t2B = t1B + s2B;
    const float s3B = fmaf(t2B, a3B, c3);
    const float t3B = t2B + s3B;

    // Single update pass: out = x * t3 + (b1+b2+b3). NT stores (write-once).
    float* orowA = out + (size_t)rowA * CN_DIM;
    float* orowB = orowA + CN_DIM;
#pragma unroll
    for (int j = 0; j < 4; ++j) {
        f32x4 oA, oB;
#pragma unroll
        for (int c = 0; c < 4; ++c) {
            oA[c] = fmaf(x0A[j][c], t3A, Bs[j][c]);
            oB[c] = fmaf(x0B[j][c], t3B, Bs[j][c]);
        }
        __builtin_nontemporal_store(oA,
            reinterpret_cast<f32x4*>(orowA + j * 256 + eoff));
        __builtin_nontemporal_store(oB,
            reinterpret_cast<f32x4*>(orowB + j * 256 + eoff));
    }
}

extern "C" void kernel_launch(void* const* d_in, const int* in_sizes, int n_in,
                              void* d_out, int out_size, void* d_ws, size_t ws_size,
                              hipStream_t stream) {
    const float* x       = (const float*)d_in[0];
    const float* kernels = (const float*)d_in[1];
    const float* bias    = (const float*)d_in[2];
    float* out           = (float*)d_out;

    // 2 rows/wave, 4 waves/block -> 8 rows/block, 2048 blocks (8/CU).
    dim3 grid(CN_BATCH / 8);
    dim3 block(256);
    crossnet_kernel<<<grid, block, 0, stream>>>(x, kernels, bias, out);
}